// Round 1
// 1943.942 us; speedup vs baseline: 1.0880x; 1.0880x over previous
//
#include <hip/hip_runtime.h>

// ---------------- problem constants ----------------
#define BB    128
#define BUFF  64
#define STK   48
#define NCOMP 8
#define HIST  96
#define WDIM  300
#define POSD  50
#define CAD   50
#define HAD   50
#define FC    128
#define UU    256
#define NOUT  82

typedef __bf16 bf16;
typedef __attribute__((ext_vector_type(8))) __bf16 bf16x8;
typedef __attribute__((ext_vector_type(4))) float   f32x4;

__device__ __forceinline__ float sigf(float x)   { return 1.f / (1.f + __expf(-x)); }
__device__ __forceinline__ float tanhf_(float x) { return 1.f - 2.f / (1.f + __expf(2.f * x)); }

// pack two consecutive fp32 values as two bf16 in one u32
__device__ __forceinline__ unsigned pack2(const float* p) {
  union { unsigned u; bf16 h[2]; } r;
  r.h[0] = (bf16)p[0]; r.h[1] = (bf16)p[1];
  return r.u;
}

// =====================================================================
// Kernel 1: embedding MLP.  rows 0..98303 = comp, 98304..106495 = buff.
// out = relu(concat(w_emb[word](300), p_emb[pos](50)) @ emb_W(350x128) + b)
// =====================================================================
__global__ __launch_bounds__(256) void k_emb(
    const int* bw, const int* bp, const int* cw, const int* cp,
    const float* w_emb, const float* p_emb, const float* embW, const float* embB,
    bf16* comp_emb, bf16* buff_emb)
{
  __shared__ __align__(16) char sm[138752];
  bf16*  A  = (bf16*)sm;                    // [64][360]
  bf16*  Wt = (bf16*)(sm + 46080);          // [128][360] (transposed: [n][k])
  float* sb = (float*)(sm + 46080 + 92160); // [128]

  const int tid = threadIdx.x;
  const int r0  = blockIdx.x * 64;

  // stage A rows (word||pos||0), converting fp32 -> bf16, 2 per u32
  for (int i = tid; i < 64 * 176; i += 256) {
    int m = i / 176, c2 = i % 176, e0 = 2 * c2;
    int r = r0 + m;
    unsigned v;
    if (e0 < 300) {
      int word = (r < 98304) ? cw[r] : bw[r - 98304];
      v = pack2(w_emb + word * 300 + e0);
    } else if (e0 < 350) {
      int pos = (r < 98304) ? cp[r] : bp[r - 98304];
      v = pack2(p_emb + pos * 50 + (e0 - 300));
    } else v = 0u;
    *(unsigned*)(A + m * 360 + e0) = v;
  }
  // stage W transposed (fp32 -> bf16)
  for (int i = tid; i < 350 * 128; i += 256) {
    int k = i >> 7, n = i & 127;
    Wt[n * 360 + k] = (bf16)embW[i];
  }
  // zero k=350,351 in Wt
  { int i = tid; if (i < 256) { int n = i >> 1; Wt[n * 360 + 350 + (i & 1)] = (bf16)0.f; } }
  if (tid < 128) sb[tid] = embB[tid];
  __syncthreads();

  const int wv = tid >> 6, lane = tid & 63, l15 = lane & 15, quad = lane >> 4;
  f32x4 acc[8];
#pragma unroll
  for (int i = 0; i < 8; ++i) acc[i] = (f32x4){0.f, 0.f, 0.f, 0.f};

  const bf16* Arow = A + (wv * 16 + l15) * 360;
  for (int ks = 0; ks < 11; ++ks) {
    int kq = ks * 32 + quad * 8;
    bf16x8 a = *(const bf16x8*)(Arow + kq);
#pragma unroll
    for (int nt = 0; nt < 8; ++nt) {
      bf16x8 b = *(const bf16x8*)(Wt + (nt * 16 + l15) * 360 + kq);
      acc[nt] = __builtin_amdgcn_mfma_f32_16x16x32_bf16(a, b, acc[nt], 0, 0, 0);
    }
  }
#pragma unroll
  for (int nt = 0; nt < 8; ++nt)
#pragma unroll
    for (int rr = 0; rr < 4; ++rr) {
      int row = wv * 16 + quad * 4 + rr;
      int n   = nt * 16 + l15;
      float z = fmaxf(acc[nt][rr] + sb[n], 0.f);
      int r = r0 + row;
      bf16 o = (bf16)z;
      if (r < 98304) comp_emb[r * 128 + n] = o;
      else           buff_emb[(r - 98304) * 128 + n] = o;
    }
}

// =====================================================================
// Kernel 2: compose.  16 (b,s) pairs per block, 8 sequential steps in LDS.
// =====================================================================
__global__ __launch_bounds__(256) void k_compose(
    const int* cw, const int* caid, const int* calen,
    const bf16* comp_emb, const float* ca_emb, const float* recW, const float* recB,
    bf16* stack_emb)
{
  __shared__ __align__(16) char sm[129344];
  bf16*  Wt   = (bf16*)sm;              // [128][328]
  bf16*  X    = (bf16*)(sm + 83968);    // [16][328]
  bf16*  VALS = (bf16*)(sm + 94464);    // [16][8][128]
  float* recb = (float*)(sm + 127232);  // [128]
  int*   IH   = (int*)(sm + 127744);    // [16][8]
  int*   ID   = (int*)(sm + 128256);
  int*   AN   = (int*)(sm + 128768);
  int*   ALEN = (int*)(sm + 129280);    // [16]

  const int tid = threadIdx.x;
  const int bs0 = blockIdx.x * 16;

  for (int i = tid; i < 306 * 128; i += 256) {
    int k = i >> 7, n = i & 127;
    Wt[n * 328 + k] = (bf16)recW[i];
  }
  for (int i = tid; i < 128 * 22; i += 256) {  // zero pad rows 306..327
    int n = i / 22, k = 306 + i % 22;
    Wt[n * 328 + k] = (bf16)0.f;
  }
  if (tid < 128) recb[tid] = recB[tid];
  if (tid < 16) {
    int bs = bs0 + tid;
    int hid[8], did[8];
#pragma unroll
    for (int m = 0; m < 8; ++m) { hid[m] = cw[bs * 16 + 2 * m]; did[m] = cw[bs * 16 + 2 * m + 1]; }
    for (int n = 0; n < 8; ++n) {
      int ih = -1, idd = -1;
      for (int m = 0; m < n; ++m) { if (hid[m] == hid[n]) ih = m; if (hid[m] == did[n]) idd = m; }
      IH[tid * 8 + n] = ih; ID[tid * 8 + n] = idd; AN[tid * 8 + n] = caid[bs * 8 + n];
    }
    ALEN[tid] = calen[bs];
  }
  __syncthreads();

  const int wv = tid >> 6, lane = tid & 63, l15 = lane & 15, quad = lane >> 4;

  for (int n = 0; n < 8; ++n) {
    // stage X = [head_e(128) | act(50) | dep_e(128) | 0 pad] per pair
    for (int i = tid; i < 16 * 160; i += 256) {
      int p = i / 160, c2 = i % 160, e0 = 2 * c2;
      int bs = bs0 + p;
      unsigned v;
      if (e0 < 128) {
        int ih = IH[p * 8 + n];
        v = (ih >= 0) ? *(const unsigned*)(VALS + (p * 8 + ih) * 128 + e0)
                      : *(const unsigned*)(comp_emb + (bs * 16 + 2 * n) * 128 + e0);
      } else if (e0 < 178) {
        v = pack2(ca_emb + AN[p * 8 + n] * 50 + (e0 - 128));
      } else if (e0 < 306) {
        int e = e0 - 178;
        int idd = ID[p * 8 + n];
        v = (idd >= 0) ? *(const unsigned*)(VALS + (p * 8 + idd) * 128 + e)
                       : *(const unsigned*)(comp_emb + (bs * 16 + 2 * n + 1) * 128 + e);
      } else v = 0u;
      *(unsigned*)(X + p * 328 + e0) = v;
    }
    __syncthreads();

    f32x4 acc[2];
    acc[0] = (f32x4){0.f,0.f,0.f,0.f}; acc[1] = (f32x4){0.f,0.f,0.f,0.f};
    for (int ks = 0; ks < 10; ++ks) {
      int kq = ks * 32 + quad * 8;
      bf16x8 a = *(const bf16x8*)(X + l15 * 328 + kq);
#pragma unroll
      for (int t2 = 0; t2 < 2; ++t2) {
        int nt = 2 * wv + t2;
        bf16x8 b = *(const bf16x8*)(Wt + (nt * 16 + l15) * 328 + kq);
        acc[t2] = __builtin_amdgcn_mfma_f32_16x16x32_bf16(a, b, acc[t2], 0, 0, 0);
      }
    }
    __syncthreads();
#pragma unroll
    for (int t2 = 0; t2 < 2; ++t2) {
      int nt = 2 * wv + t2;
#pragma unroll
      for (int rr = 0; rr < 4; ++rr) {
        int p = quad * 4 + rr;
        int col = nt * 16 + l15;
        VALS[(p * 8 + n) * 128 + col] = (bf16)tanhf_(acc[t2][rr] + recb[col]);
      }
    }
    __syncthreads();
  }

  for (int i = tid; i < 16 * 64; i += 256) {
    int p = i / 64, c2 = i % 64, e0 = 2 * c2;
    int bs = bs0 + p;
    int al = ALEN[p];
    unsigned v = (al == 0) ? *(const unsigned*)(comp_emb + (bs * 16) * 128 + e0)
                           : *(const unsigned*)(VALS + (p * 8 + (al - 1)) * 128 + e0);
    *(unsigned*)(stack_emb + bs * 128 + e0) = v;
  }
}

// =====================================================================
// Kernel 3: persistent 3x 2-layer masked LSTM.
// 48 blocks: L = bx/16; within: layer = (bx%16)/8, uchunk = bx%8
// (32 u-columns of all 4 gates).  Phase p: L0 computes step p, L1 computes
// step p-1 (skewed) -> one inter-block barrier per phase.
//
// THIS ROUND: h-state loads were relaxed agent-scope ATOMIC loads inside a
// runtime-trip-count K-loop -> LLVM neither unrolled nor pipelined them ->
// 16 serialized MALL round trips per phase (~11us of the 14.4us phase).
// Now: body templated on (L,layer) so all loops are compile-time; all h
// fragments for the phase are batch-issued up front as plain
// global_load_dwordx4 sc0 sc1 (same MALL-coherent bypass semantics as the
// atomics; ordering still provided by __syncthreads vmcnt drain + barrier),
// then ONE s_waitcnt vmcnt(0) + sched_barrier(0) before consumption.
// One exposed latency per phase instead of 16.
// LDS pins 1 block/CU -> launch_bounds(256,1) frees VGPR budget to 512 so
// 32 in-flight 16B results (128 VGPRs) fit without spill.
// =====================================================================
struct BarT { int cnt; int pad[31]; };

template<int L, int LAYER>
__device__ __forceinline__ void lstm_role(
    const float* W, const float* bias,
    const bf16* xsrc, const float* hist_tab, const int* hist_id,
    const int* lenp, bf16* h0w, bf16* h1w, BarT* bar, char* sm, int u0)
{
  constexpr int T   = (L == 0) ? STK : (L == 1) ? BUFF : HIST;
  constexpr int K   = (LAYER == 0) ? ((L == 2) ? 320 : 384) : 512;
  constexpr int KP  = K + 8;
  constexpr int Kxp = (LAYER == 0) ? ((L == 2) ? 64 : 128) : 256;
  constexpr int Tx  = (L == 0) ? STK : BUFF;

  const int tid = threadIdx.x;
  bf16*  Wt     = (bf16*)sm;                               // [128][KP]
  bf16*  hstage = (bf16*)(sm + 128 * KP * 2);              // [128][36]
  float* sb     = (float*)(sm + 128 * KP * 2 + 9216);      // [128]
  bf16*  Xa     = (bf16*)(sm + 128 * KP * 2 + 9216 + 512); // [128][72] (action L0)

  // stage weight slice, transposed: Wt[cc][kk], cc = gate*32 + within
  for (int i = tid; i < K * 128; i += 256) {
    int kk = i >> 7, cc = i & 127;
    int col = (cc >> 5) * 256 + u0 + (cc & 31);
    bf16 v;
    if (LAYER == 0 && L == 2) {
      if (kk < 64) v = (kk < 50) ? (bf16)W[kk * 1024 + col] : (bf16)0.f;
      else         v = (bf16)W[(kk - 14) * 1024 + col];
    } else v = (bf16)W[kk * 1024 + col];
    Wt[cc * KP + kk] = v;
  }
  if (tid < 128) { int col = (tid >> 5) * 256 + u0 + (tid & 31); sb[tid] = bias[col]; }

  const int wv = tid >> 6, lane = tid & 63, l15 = lane & 15, quad = lane >> 4;
  int lenr[8];
#pragma unroll
  for (int mt = 0; mt < 2; ++mt)
#pragma unroll
    for (int rr = 0; rr < 4; ++rr)
      lenr[mt * 4 + rr] = lenp[32 * wv + 16 * mt + quad * 4 + rr];

  float cst[16], hst[16];
#pragma unroll
  for (int i = 0; i < 16; ++i) { cst[i] = 0.f; hst[i] = 0.f; }

  const int row0 = 32 * wv + l15;

  __syncthreads();

  for (int p = 0; p <= T; ++p) {
    const bool active = (LAYER == 0) ? (p < T) : (p >= 1);
    const int  t = (LAYER == 0) ? p : (p - 1);

    if (L == 2 && LAYER == 0 && active) {  // stage action x_t (50 -> 64 padded)
      for (int i = tid; i < 128 * 32; i += 256) {
        int row = i >> 5, e0 = 2 * (i & 31);
        unsigned v = 0u;
        if (e0 < 50) { int id = hist_id[row * 96 + t]; v = pack2(hist_tab + id * 50 + e0); }
        *(unsigned*)(Xa + row * 72 + e0) = v;
      }
    }
    __syncthreads();

    if (active) {
      const bf16* h0r = h0w + ((p - 1) & 1) * 32768;
      const bf16* h1r = h1w + (p & 1) * 32768;

      // ---- batch-issue ALL h-state bypass loads for this phase ----
      bf16x8 hA[16];
#pragma unroll
      for (int hk = 0; hk < 8; ++hk)
#pragma unroll
        for (int mt = 0; mt < 2; ++mt) {
          const bf16* pa = h0r + (row0 + 16 * mt) * 256 + hk * 32 + quad * 8;
          asm volatile("global_load_dwordx4 %0, %1, off sc0 sc1"
                       : "=v"(hA[hk * 2 + mt]) : "v"(pa) : "memory");
        }
      bf16x8 hB[16];
      if (LAYER == 1) {
#pragma unroll
        for (int hk = 0; hk < 8; ++hk)
#pragma unroll
          for (int mt = 0; mt < 2; ++mt) {
            const bf16* pb = h1r + (row0 + 16 * mt) * 256 + hk * 32 + quad * 8;
            asm volatile("global_load_dwordx4 %0, %1, off sc0 sc1"
                         : "=v"(hB[hk * 2 + mt]) : "v"(pb) : "memory");
          }
      }

      f32x4 acc[2][8];
#pragma unroll
      for (int a1 = 0; a1 < 2; ++a1)
#pragma unroll
        for (int a2 = 0; a2 < 8; ++a2) acc[a1][a2] = (f32x4){0.f, 0.f, 0.f, 0.f};

      // ---- X part (layer0 only); overlaps the in-flight h loads ----
      if (LAYER == 0) {
#pragma unroll
        for (int ks = 0; ks < Kxp / 32; ++ks) {
          int kq = ks * 32 + quad * 8;
          bf16x8 a[2];
#pragma unroll
          for (int mt = 0; mt < 2; ++mt) {
            int row = row0 + 16 * mt;
            if (L == 2) a[mt] = *(const bf16x8*)(Xa + row * 72 + kq);
            else        a[mt] = *(const bf16x8*)(xsrc + (row * Tx + t) * 128 + kq);
          }
#pragma unroll
          for (int nt = 0; nt < 8; ++nt) {
            bf16x8 b = *(const bf16x8*)(Wt + (nt * 16 + l15) * KP + kq);
            acc[0][nt] = __builtin_amdgcn_mfma_f32_16x16x32_bf16(a[0], b, acc[0][nt], 0, 0, 0);
            acc[1][nt] = __builtin_amdgcn_mfma_f32_16x16x32_bf16(a[1], b, acc[1][nt], 0, 0, 0);
          }
        }
      }

      // drain the batch; sched_barrier keeps MFMAs from hoisting above it
      asm volatile("s_waitcnt vmcnt(0)" ::: "memory");
      __builtin_amdgcn_sched_barrier(0);

      // ---- H0 part (8 ksteps from hA) ----
      constexpr int HB0 = (LAYER == 0) ? Kxp : 0;
#pragma unroll
      for (int hk = 0; hk < 8; ++hk) {
        int kq = HB0 + hk * 32 + quad * 8;
#pragma unroll
        for (int nt = 0; nt < 8; ++nt) {
          bf16x8 b = *(const bf16x8*)(Wt + (nt * 16 + l15) * KP + kq);
          acc[0][nt] = __builtin_amdgcn_mfma_f32_16x16x32_bf16(hA[hk * 2 + 0], b, acc[0][nt], 0, 0, 0);
          acc[1][nt] = __builtin_amdgcn_mfma_f32_16x16x32_bf16(hA[hk * 2 + 1], b, acc[1][nt], 0, 0, 0);
        }
      }
      // ---- H1 part (layer1 only, 8 ksteps from hB) ----
      if (LAYER == 1) {
#pragma unroll
        for (int hk = 0; hk < 8; ++hk) {
          int kq = 256 + hk * 32 + quad * 8;
#pragma unroll
          for (int nt = 0; nt < 8; ++nt) {
            bf16x8 b = *(const bf16x8*)(Wt + (nt * 16 + l15) * KP + kq);
            acc[0][nt] = __builtin_amdgcn_mfma_f32_16x16x32_bf16(hB[hk * 2 + 0], b, acc[0][nt], 0, 0, 0);
            acc[1][nt] = __builtin_amdgcn_mfma_f32_16x16x32_bf16(hB[hk * 2 + 1], b, acc[1][nt], 0, 0, 0);
          }
        }
      }

      // gates: nt 0,1 = i ; 2,3 = j ; 4,5 = f ; 6,7 = o
#pragma unroll
      for (int mt = 0; mt < 2; ++mt)
#pragma unroll
        for (int g2 = 0; g2 < 2; ++g2)
#pragma unroll
          for (int rr = 0; rr < 4; ++rr) {
            int row = 32 * wv + 16 * mt + quad * 4 + rr;
            float zi = acc[mt][0 + g2][rr] + sb[(0 + g2) * 16 + l15];
            float zj = acc[mt][2 + g2][rr] + sb[(2 + g2) * 16 + l15];
            float zf = acc[mt][4 + g2][rr] + sb[(4 + g2) * 16 + l15];
            float zo = acc[mt][6 + g2][rr] + sb[(6 + g2) * 16 + l15];
            float ig = sigf(zi), jg = tanhf_(zj), fg = sigf(zf + 1.f), og = sigf(zo);
            int idx = mt * 8 + g2 * 4 + rr;
            float cn = cst[idx] * fg + ig * jg;
            float hn = tanhf_(cn) * og;
            bool mk = (t < lenr[mt * 4 + rr]);
            cst[idx] = mk ? cn : cst[idx];
            hst[idx] = mk ? hn : hst[idx];
            hstage[row * 36 + g2 * 16 + l15] = (bf16)hst[idx];
          }
    }
    __syncthreads();
    if (active) {
      bf16* dst = (LAYER == 0) ? (h0w + (p & 1) * 32768) : (h1w + ((p - 1) & 1) * 32768);
      for (int i = tid; i < 128 * 8; i += 256) {
        int row = i >> 3, c = i & 7;
        unsigned long long v = *(const unsigned long long*)(hstage + row * 36 + c * 4);
        __hip_atomic_store((unsigned long long*)(dst + row * 256 + u0 + c * 4), v,
                           __ATOMIC_RELAXED, __HIP_MEMORY_SCOPE_AGENT);
      }
    }
    // inter-block barrier: monotone relaxed counter (16 participants/LSTM).
    // __syncthreads (below and in-loop) drains each thread's vmcnt, so all
    // sc1 h-stores are at the coherence point before the arrival add.
    // Skipped on the final phase: nothing polls past it, and k_final's
    // dependency is the stream ordering.
    if (p < T) {
      __syncthreads();
      if (tid == 0) {
        __builtin_amdgcn_sched_barrier(0);
        const int target = 16 * (p + 1);
        int prev = __hip_atomic_fetch_add(&bar->cnt, 1, __ATOMIC_RELAXED, __HIP_MEMORY_SCOPE_AGENT);
        if (prev != target - 1) {
          while (__hip_atomic_load(&bar->cnt, __ATOMIC_RELAXED, __HIP_MEMORY_SCOPE_AGENT) < target) { }
        }
        __builtin_amdgcn_sched_barrier(0);
      }
      __syncthreads();
    }
  }
}

__global__ __launch_bounds__(256, 1) void k_lstm(
    const float* sW0, const float* sb0, const float* sW1, const float* sb1,
    const float* bW0, const float* bb0, const float* bW1, const float* bb1,
    const float* aW0, const float* ab0, const float* aW1, const float* ab1,
    const bf16* stack_emb, const bf16* buff_emb, const float* hist_tab, const int* hist_id,
    const int* len_s, const int* len_b, const int* len_a,
    bf16* h0buf, bf16* h1buf, BarT* bars)
{
  __shared__ __align__(16) char sm[143872];
  const int bx    = blockIdx.x;
  const int L     = bx >> 4;
  const int rid   = bx & 15;
  const int layer = rid >> 3;
  const int u0    = (rid & 7) * 32;

  BarT* bar = bars + L;
  bf16* h0w = h0buf + L * 2 * 32768;  // [2][128][256]
  bf16* h1w = h1buf + L * 2 * 32768;

  if (L == 0) {
    if (layer == 0) lstm_role<0, 0>(sW0, sb0, stack_emb, hist_tab, hist_id, len_s, h0w, h1w, bar, sm, u0);
    else            lstm_role<0, 1>(sW1, sb1, stack_emb, hist_tab, hist_id, len_s, h0w, h1w, bar, sm, u0);
  } else if (L == 1) {
    if (layer == 0) lstm_role<1, 0>(bW0, bb0, buff_emb, hist_tab, hist_id, len_b, h0w, h1w, bar, sm, u0);
    else            lstm_role<1, 1>(bW1, bb1, buff_emb, hist_tab, hist_id, len_b, h0w, h1w, bar, sm, u0);
  } else {
    if (layer == 0) lstm_role<2, 0>(aW0, ab0, nullptr, hist_tab, hist_id, len_a, h0w, h1w, bar, sm, u0);
    else            lstm_role<2, 1>(aW1, ab1, nullptr, hist_tab, hist_id, len_a, h0w, h1w, bar, sm, u0);
  }
}

// =====================================================================
// Kernel 4: out = concat(h_s,h_b,h_a) @ fW + fb
// =====================================================================
__global__ __launch_bounds__(128) void k_final(
    const bf16* h1buf, const float* fW, const float* fb, float* out)
{
  __shared__ float hs[768];
  const int b = blockIdx.x, tid = threadIdx.x;
  for (int i = tid; i < 768; i += 128) {
    int L = i >> 8, u = i & 255;
    hs[i] = (float)h1buf[(L * 2 + 1) * 32768 + b * 256 + u];  // final parity = 1 (T even)
  }
  __syncthreads();
  if (tid < NOUT) {
    float acc = fb[tid];
    for (int u = 0; u < 768; ++u) acc += hs[u] * fW[u * NOUT + tid];
    out[b * NOUT + tid] = acc;
  }
}

// =====================================================================
extern "C" void kernel_launch(void* const* d_in, const int* in_sizes, int n_in,
                              void* d_out, int out_size, void* d_ws, size_t ws_size,
                              hipStream_t stream)
{
  (void)in_sizes; (void)n_in; (void)out_size; (void)ws_size;
  char* ws = (char*)d_ws;
  BarT* bars      = (BarT*)ws;                             // 512 B reserved
  bf16* h0buf     = (bf16*)(ws + 512);                     // 3*2*128*256*2 = 393216
  bf16* h1buf     = (bf16*)(ws + 512 + 393216);            // 393216
  bf16* comp_emb  = (bf16*)(ws + 786944);                  // 98304*128*2 = 25165824
  bf16* buff_emb  = (bf16*)(ws + 786944 + 25165824);       // 8192*128*2  = 2097152
  bf16* stack_emb = (bf16*)(ws + 786944 + 25165824 + 2097152); // 6144*128*2 = 1572864

  hipMemsetAsync(ws, 0, 786944, stream);  // barriers + h0/h1 init state

  k_emb<<<1664, 256, 0, stream>>>(
      (const int*)d_in[0], (const int*)d_in[1], (const int*)d_in[2], (const int*)d_in[3],
      (const float*)d_in[13], (const float*)d_in[10], (const float*)d_in[14], (const float*)d_in[15],
      comp_emb, buff_emb);

  k_compose<<<384, 256, 0, stream>>>(
      (const int*)d_in[2], (const int*)d_in[4], (const int*)d_in[5],
      comp_emb, (const float*)d_in[11], (const float*)d_in[16], (const float*)d_in[17],
      stack_emb);

  k_lstm<<<48, 256, 0, stream>>>(
      (const float*)d_in[18], (const float*)d_in[19], (const float*)d_in[20], (const float*)d_in[21],
      (const float*)d_in[22], (const float*)d_in[23], (const float*)d_in[24], (const float*)d_in[25],
      (const float*)d_in[26], (const float*)d_in[27], (const float*)d_in[28], (const float*)d_in[29],
      stack_emb, buff_emb, (const float*)d_in[12], (const int*)d_in[6],
      (const int*)d_in[7], (const int*)d_in[8], (const int*)d_in[9],
      h0buf, h1buf, bars);

  k_final<<<128, 128, 0, stream>>>(h1buf, (const float*)d_in[30], (const float*)d_in[31],
                                   (float*)d_out);
}

// Round 3
// 1888.180 us; speedup vs baseline: 1.1202x; 1.0295x over previous
//
#include <hip/hip_runtime.h>

// ---------------- problem constants ----------------
#define BB    128
#define BUFF  64
#define STK   48
#define NCOMP 8
#define HIST  96
#define WDIM  300
#define POSD  50
#define CAD   50
#define HAD   50
#define FC    128
#define UU    256
#define NOUT  82

typedef __bf16 bf16;
typedef __attribute__((ext_vector_type(8))) __bf16 bf16x8;
typedef __attribute__((ext_vector_type(4))) float   f32x4;

__device__ __forceinline__ float sigf(float x)   { return 1.f / (1.f + __expf(-x)); }
__device__ __forceinline__ float tanhf_(float x) { return 1.f - 2.f / (1.f + __expf(2.f * x)); }

// pack two consecutive fp32 values as two bf16 in one u32
__device__ __forceinline__ unsigned pack2(const float* p) {
  union { unsigned u; bf16 h[2]; } r;
  r.h[0] = (bf16)p[0]; r.h[1] = (bf16)p[1];
  return r.u;
}

// =====================================================================
// Kernel 1: embedding MLP.  rows 0..98303 = comp, 98304..106495 = buff.
// out = relu(concat(w_emb[word](300), p_emb[pos](50)) @ emb_W(350x128) + b)
// =====================================================================
__global__ __launch_bounds__(256) void k_emb(
    const int* bw, const int* bp, const int* cw, const int* cp,
    const float* w_emb, const float* p_emb, const float* embW, const float* embB,
    bf16* comp_emb, bf16* buff_emb)
{
  __shared__ __align__(16) char sm[138752];
  bf16*  A  = (bf16*)sm;                    // [64][360]
  bf16*  Wt = (bf16*)(sm + 46080);          // [128][360] (transposed: [n][k])
  float* sb = (float*)(sm + 46080 + 92160); // [128]

  const int tid = threadIdx.x;
  const int r0  = blockIdx.x * 64;

  // stage A rows (word||pos||0), converting fp32 -> bf16, 2 per u32
  for (int i = tid; i < 64 * 176; i += 256) {
    int m = i / 176, c2 = i % 176, e0 = 2 * c2;
    int r = r0 + m;
    unsigned v;
    if (e0 < 300) {
      int word = (r < 98304) ? cw[r] : bw[r - 98304];
      v = pack2(w_emb + word * 300 + e0);
    } else if (e0 < 350) {
      int pos = (r < 98304) ? cp[r] : bp[r - 98304];
      v = pack2(p_emb + pos * 50 + (e0 - 300));
    } else v = 0u;
    *(unsigned*)(A + m * 360 + e0) = v;
  }
  // stage W transposed (fp32 -> bf16)
  for (int i = tid; i < 350 * 128; i += 256) {
    int k = i >> 7, n = i & 127;
    Wt[n * 360 + k] = (bf16)embW[i];
  }
  // zero k=350,351 in Wt
  { int i = tid; if (i < 256) { int n = i >> 1; Wt[n * 360 + 350 + (i & 1)] = (bf16)0.f; } }
  if (tid < 128) sb[tid] = embB[tid];
  __syncthreads();

  const int wv = tid >> 6, lane = tid & 63, l15 = lane & 15, quad = lane >> 4;
  f32x4 acc[8];
#pragma unroll
  for (int i = 0; i < 8; ++i) acc[i] = (f32x4){0.f, 0.f, 0.f, 0.f};

  const bf16* Arow = A + (wv * 16 + l15) * 360;
  for (int ks = 0; ks < 11; ++ks) {
    int kq = ks * 32 + quad * 8;
    bf16x8 a = *(const bf16x8*)(Arow + kq);
#pragma unroll
    for (int nt = 0; nt < 8; ++nt) {
      bf16x8 b = *(const bf16x8*)(Wt + (nt * 16 + l15) * 360 + kq);
      acc[nt] = __builtin_amdgcn_mfma_f32_16x16x32_bf16(a, b, acc[nt], 0, 0, 0);
    }
  }
#pragma unroll
  for (int nt = 0; nt < 8; ++nt)
#pragma unroll
    for (int rr = 0; rr < 4; ++rr) {
      int row = wv * 16 + quad * 4 + rr;
      int n   = nt * 16 + l15;
      float z = fmaxf(acc[nt][rr] + sb[n], 0.f);
      int r = r0 + row;
      bf16 o = (bf16)z;
      if (r < 98304) comp_emb[r * 128 + n] = o;
      else           buff_emb[(r - 98304) * 128 + n] = o;
    }
}

// =====================================================================
// Kernel 2: compose.  16 (b,s) pairs per block, 8 sequential steps in LDS.
// =====================================================================
__global__ __launch_bounds__(256) void k_compose(
    const int* cw, const int* caid, const int* calen,
    const bf16* comp_emb, const float* ca_emb, const float* recW, const float* recB,
    bf16* stack_emb)
{
  __shared__ __align__(16) char sm[129344];
  bf16*  Wt   = (bf16*)sm;              // [128][328]
  bf16*  X    = (bf16*)(sm + 83968);    // [16][328]
  bf16*  VALS = (bf16*)(sm + 94464);    // [16][8][128]
  float* recb = (float*)(sm + 127232);  // [128]
  int*   IH   = (int*)(sm + 127744);    // [16][8]
  int*   ID   = (int*)(sm + 128256);
  int*   AN   = (int*)(sm + 128768);
  int*   ALEN = (int*)(sm + 129280);    // [16]

  const int tid = threadIdx.x;
  const int bs0 = blockIdx.x * 16;

  for (int i = tid; i < 306 * 128; i += 256) {
    int k = i >> 7, n = i & 127;
    Wt[n * 328 + k] = (bf16)recW[i];
  }
  for (int i = tid; i < 128 * 22; i += 256) {  // zero pad rows 306..327
    int n = i / 22, k = 306 + i % 22;
    Wt[n * 328 + k] = (bf16)0.f;
  }
  if (tid < 128) recb[tid] = recB[tid];
  if (tid < 16) {
    int bs = bs0 + tid;
    int hid[8], did[8];
#pragma unroll
    for (int m = 0; m < 8; ++m) { hid[m] = cw[bs * 16 + 2 * m]; did[m] = cw[bs * 16 + 2 * m + 1]; }
    for (int n = 0; n < 8; ++n) {
      int ih = -1, idd = -1;
      for (int m = 0; m < n; ++m) { if (hid[m] == hid[n]) ih = m; if (hid[m] == did[n]) idd = m; }
      IH[tid * 8 + n] = ih; ID[tid * 8 + n] = idd; AN[tid * 8 + n] = caid[bs * 8 + n];
    }
    ALEN[tid] = calen[bs];
  }
  __syncthreads();

  const int wv = tid >> 6, lane = tid & 63, l15 = lane & 15, quad = lane >> 4;

  for (int n = 0; n < 8; ++n) {
    // stage X = [head_e(128) | act(50) | dep_e(128) | 0 pad] per pair
    for (int i = tid; i < 16 * 160; i += 256) {
      int p = i / 160, c2 = i % 160, e0 = 2 * c2;
      int bs = bs0 + p;
      unsigned v;
      if (e0 < 128) {
        int ih = IH[p * 8 + n];
        v = (ih >= 0) ? *(const unsigned*)(VALS + (p * 8 + ih) * 128 + e0)
                      : *(const unsigned*)(comp_emb + (bs * 16 + 2 * n) * 128 + e0);
      } else if (e0 < 178) {
        v = pack2(ca_emb + AN[p * 8 + n] * 50 + (e0 - 128));
      } else if (e0 < 306) {
        int e = e0 - 178;
        int idd = ID[p * 8 + n];
        v = (idd >= 0) ? *(const unsigned*)(VALS + (p * 8 + idd) * 128 + e)
                       : *(const unsigned*)(comp_emb + (bs * 16 + 2 * n + 1) * 128 + e);
      } else v = 0u;
      *(unsigned*)(X + p * 328 + e0) = v;
    }
    __syncthreads();

    f32x4 acc[2];
    acc[0] = (f32x4){0.f,0.f,0.f,0.f}; acc[1] = (f32x4){0.f,0.f,0.f,0.f};
    for (int ks = 0; ks < 10; ++ks) {
      int kq = ks * 32 + quad * 8;
      bf16x8 a = *(const bf16x8*)(X + l15 * 328 + kq);
#pragma unroll
      for (int t2 = 0; t2 < 2; ++t2) {
        int nt = 2 * wv + t2;
        bf16x8 b = *(const bf16x8*)(Wt + (nt * 16 + l15) * 328 + kq);
        acc[t2] = __builtin_amdgcn_mfma_f32_16x16x32_bf16(a, b, acc[t2], 0, 0, 0);
      }
    }
    __syncthreads();
#pragma unroll
    for (int t2 = 0; t2 < 2; ++t2) {
      int nt = 2 * wv + t2;
#pragma unroll
      for (int rr = 0; rr < 4; ++rr) {
        int p = quad * 4 + rr;
        int col = nt * 16 + l15;
        VALS[(p * 8 + n) * 128 + col] = (bf16)tanhf_(acc[t2][rr] + recb[col]);
      }
    }
    __syncthreads();
  }

  for (int i = tid; i < 16 * 64; i += 256) {
    int p = i / 64, c2 = i % 64, e0 = 2 * c2;
    int bs = bs0 + p;
    int al = ALEN[p];
    unsigned v = (al == 0) ? *(const unsigned*)(comp_emb + (bs * 16) * 128 + e0)
                           : *(const unsigned*)(VALS + (p * 8 + (al - 1)) * 128 + e0);
    *(unsigned*)(stack_emb + bs * 128 + e0) = v;
  }
}

// =====================================================================
// Kernel 3: persistent 3x 2-layer masked LSTM, XCD-colocated h exchange.
//
// Hang-proof redesign of the colocation attempt:
//  * Phase barrier: ALWAYS the round-1 MALL path (relaxed agent-scope
//    counter) -- proven correct & terminating.  COH only switches the
//    h-DATA path: plain stores + sc0 loads (same-XCD L2) vs sc1 MALL ops.
//  * Claim: bounded CAS scans only.  Primaries (XCD 0..2) CAS their own
//    LSTM's 16 slots; after a 100us timed wait every unclaimed block
//    scavenges all 48 slots.  256 resident blocks >= 48 claimants, so all
//    slots get claimed -> the one-time claim barrier terminates.
//  * COH decision = physical AND functional: all 16 claimants report the
//    same XCC_ID [learn_hip m09], AND a probe test passes (plain-store a
//    token, MALL barrier, sc0-read all 16 -- the exact op pair h uses).
//    A wrong decision degrades to COH=0 (= round-1 kernel), never a hang.
// Ordering (COH=1): __syncthreads drains vmcnt, so plain h-stores are in
// the shared XCD L2 before the barrier arrival; peers' sc0 loads bypass
// their L1 and hit that L2.  k_final sees h1buf via end-of-kernel L2
// writeback (standard kernel-boundary coherence).
// =====================================================================
struct BarT { int cnt; int pad[31]; };

template<bool COH>
__device__ __forceinline__ bf16x8 hload(const bf16* p) {
  bf16x8 v;
  if constexpr (COH)
    asm volatile("global_load_dwordx4 %0, %1, off sc0" : "=v"(v) : "v"(p) : "memory");
  else
    asm volatile("global_load_dwordx4 %0, %1, off sc0 sc1" : "=v"(v) : "v"(p) : "memory");
  return v;
}

template<bool COH>
__device__ __forceinline__ void hstore(bf16* p, unsigned long long v) {
  if constexpr (COH)
    asm volatile("global_store_dwordx2 %0, %1, off" :: "v"(p), "v"(v) : "memory");
  else
    __hip_atomic_store((unsigned long long*)p, v, __ATOMIC_RELAXED, __HIP_MEMORY_SCOPE_AGENT);
}

template<int L, int LAYER, bool COH>
__device__ __forceinline__ void lstm_role(
    const float* W, const float* bias,
    const bf16* xsrc, const float* hist_tab, const int* hist_id,
    const int* lenp, bf16* h0w, bf16* h1w, BarT* bar, char* sm, int u0)
{
  constexpr int T   = (L == 0) ? STK : (L == 1) ? BUFF : HIST;
  constexpr int K   = (LAYER == 0) ? ((L == 2) ? 320 : 384) : 512;
  constexpr int KP  = K + 8;
  constexpr int Kxp = (LAYER == 0) ? ((L == 2) ? 64 : 128) : 256;
  constexpr int Tx  = (L == 0) ? STK : BUFF;

  const int tid = threadIdx.x;
  bf16*  Wt     = (bf16*)sm;                               // [128][KP]
  bf16*  hstage = (bf16*)(sm + 128 * KP * 2);              // [128][36]
  float* sb     = (float*)(sm + 128 * KP * 2 + 9216);      // [128]
  bf16*  Xa     = (bf16*)(sm + 128 * KP * 2 + 9216 + 512); // [128][72] (action L0)

  // stage weight slice, transposed: Wt[cc][kk], cc = gate*32 + within
  for (int i = tid; i < K * 128; i += 256) {
    int kk = i >> 7, cc = i & 127;
    int col = (cc >> 5) * 256 + u0 + (cc & 31);
    bf16 v;
    if (LAYER == 0 && L == 2) {
      if (kk < 64) v = (kk < 50) ? (bf16)W[kk * 1024 + col] : (bf16)0.f;
      else         v = (bf16)W[(kk - 14) * 1024 + col];
    } else v = (bf16)W[kk * 1024 + col];
    Wt[cc * KP + kk] = v;
  }
  if (tid < 128) { int col = (tid >> 5) * 256 + u0 + (tid & 31); sb[tid] = bias[col]; }

  const int wv = tid >> 6, lane = tid & 63, l15 = lane & 15, quad = lane >> 4;
  int lenr[8];
#pragma unroll
  for (int mt = 0; mt < 2; ++mt)
#pragma unroll
    for (int rr = 0; rr < 4; ++rr)
      lenr[mt * 4 + rr] = lenp[32 * wv + 16 * mt + quad * 4 + rr];

  float cst[16], hst[16];
#pragma unroll
  for (int i = 0; i < 16; ++i) { cst[i] = 0.f; hst[i] = 0.f; }

  const int row0 = 32 * wv + l15;

  __syncthreads();

  for (int p = 0; p <= T; ++p) {
    const bool active = (LAYER == 0) ? (p < T) : (p >= 1);
    const int  t = (LAYER == 0) ? p : (p - 1);

    if (L == 2 && LAYER == 0 && active) {  // stage action x_t (50 -> 64 padded)
      for (int i = tid; i < 128 * 32; i += 256) {
        int row = i >> 5, e0 = 2 * (i & 31);
        unsigned v = 0u;
        if (e0 < 50) { int id = hist_id[row * 96 + t]; v = pack2(hist_tab + id * 50 + e0); }
        *(unsigned*)(Xa + row * 72 + e0) = v;
      }
    }
    __syncthreads();

    if (active) {
      const bf16* h0r = h0w + ((p - 1) & 1) * 32768;
      const bf16* h1r = h1w + (p & 1) * 32768;

      // ---- batch-issue ALL h-state loads for this phase ----
      bf16x8 hA[16];
#pragma unroll
      for (int hk = 0; hk < 8; ++hk)
#pragma unroll
        for (int mt = 0; mt < 2; ++mt)
          hA[hk * 2 + mt] = hload<COH>(h0r + (row0 + 16 * mt) * 256 + hk * 32 + quad * 8);
      bf16x8 hB[16];
      if (LAYER == 1) {
#pragma unroll
        for (int hk = 0; hk < 8; ++hk)
#pragma unroll
          for (int mt = 0; mt < 2; ++mt)
            hB[hk * 2 + mt] = hload<COH>(h1r + (row0 + 16 * mt) * 256 + hk * 32 + quad * 8);
      }

      f32x4 acc[2][8];
#pragma unroll
      for (int a1 = 0; a1 < 2; ++a1)
#pragma unroll
        for (int a2 = 0; a2 < 8; ++a2) acc[a1][a2] = (f32x4){0.f, 0.f, 0.f, 0.f};

      // ---- X part (layer0 only); overlaps the in-flight h loads ----
      if (LAYER == 0) {
#pragma unroll
        for (int ks = 0; ks < Kxp / 32; ++ks) {
          int kq = ks * 32 + quad * 8;
          bf16x8 a[2];
#pragma unroll
          for (int mt = 0; mt < 2; ++mt) {
            int row = row0 + 16 * mt;
            if (L == 2) a[mt] = *(const bf16x8*)(Xa + row * 72 + kq);
            else        a[mt] = *(const bf16x8*)(xsrc + (row * Tx + t) * 128 + kq);
          }
#pragma unroll
          for (int nt = 0; nt < 8; ++nt) {
            bf16x8 b = *(const bf16x8*)(Wt + (nt * 16 + l15) * KP + kq);
            acc[0][nt] = __builtin_amdgcn_mfma_f32_16x16x32_bf16(a[0], b, acc[0][nt], 0, 0, 0);
            acc[1][nt] = __builtin_amdgcn_mfma_f32_16x16x32_bf16(a[1], b, acc[1][nt], 0, 0, 0);
          }
        }
      }

      // drain the batch; sched_barrier keeps MFMAs from hoisting above it
      asm volatile("s_waitcnt vmcnt(0)" ::: "memory");
      __builtin_amdgcn_sched_barrier(0);

      // ---- H0 part (8 ksteps from hA) ----
      constexpr int HB0 = (LAYER == 0) ? Kxp : 0;
#pragma unroll
      for (int hk = 0; hk < 8; ++hk) {
        int kq = HB0 + hk * 32 + quad * 8;
#pragma unroll
        for (int nt = 0; nt < 8; ++nt) {
          bf16x8 b = *(const bf16x8*)(Wt + (nt * 16 + l15) * KP + kq);
          acc[0][nt] = __builtin_amdgcn_mfma_f32_16x16x32_bf16(hA[hk * 2 + 0], b, acc[0][nt], 0, 0, 0);
          acc[1][nt] = __builtin_amdgcn_mfma_f32_16x16x32_bf16(hA[hk * 2 + 1], b, acc[1][nt], 0, 0, 0);
        }
      }
      // ---- H1 part (layer1 only, 8 ksteps from hB) ----
      if (LAYER == 1) {
#pragma unroll
        for (int hk = 0; hk < 8; ++hk) {
          int kq = 256 + hk * 32 + quad * 8;
#pragma unroll
          for (int nt = 0; nt < 8; ++nt) {
            bf16x8 b = *(const bf16x8*)(Wt + (nt * 16 + l15) * KP + kq);
            acc[0][nt] = __builtin_amdgcn_mfma_f32_16x16x32_bf16(hB[hk * 2 + 0], b, acc[0][nt], 0, 0, 0);
            acc[1][nt] = __builtin_amdgcn_mfma_f32_16x16x32_bf16(hB[hk * 2 + 1], b, acc[1][nt], 0, 0, 0);
          }
        }
      }

      // gates: nt 0,1 = i ; 2,3 = j ; 4,5 = f ; 6,7 = o
#pragma unroll
      for (int mt = 0; mt < 2; ++mt)
#pragma unroll
        for (int g2 = 0; g2 < 2; ++g2)
#pragma unroll
          for (int rr = 0; rr < 4; ++rr) {
            int row = 32 * wv + 16 * mt + quad * 4 + rr;
            float zi = acc[mt][0 + g2][rr] + sb[(0 + g2) * 16 + l15];
            float zj = acc[mt][2 + g2][rr] + sb[(2 + g2) * 16 + l15];
            float zf = acc[mt][4 + g2][rr] + sb[(4 + g2) * 16 + l15];
            float zo = acc[mt][6 + g2][rr] + sb[(6 + g2) * 16 + l15];
            float ig = sigf(zi), jg = tanhf_(zj), fg = sigf(zf + 1.f), og = sigf(zo);
            int idx = mt * 8 + g2 * 4 + rr;
            float cn = cst[idx] * fg + ig * jg;
            float hn = tanhf_(cn) * og;
            bool mk = (t < lenr[mt * 4 + rr]);
            cst[idx] = mk ? cn : cst[idx];
            hst[idx] = mk ? hn : hst[idx];
            hstage[row * 36 + g2 * 16 + l15] = (bf16)hst[idx];
          }
    }
    __syncthreads();
    if (active) {
      bf16* dst = (LAYER == 0) ? (h0w + (p & 1) * 32768) : (h1w + ((p - 1) & 1) * 32768);
      for (int i = tid; i < 128 * 8; i += 256) {
        int row = i >> 3, c = i & 7;
        unsigned long long v = *(const unsigned long long*)(hstage + row * 36 + c * 4);
        hstore<COH>(dst + row * 256 + u0 + c * 4, v);
      }
    }
    // inter-block barrier (16 participants/LSTM), ALWAYS the MALL path.
    // __syncthreads (below and in-loop) drains each thread's vmcnt, so all
    // h-stores are at their coherence point (shared L2 if COH, MALL else)
    // before the arrival add.  Skipped on the final phase.
    if (p < T) {
      __syncthreads();
      if (tid == 0) {
        __builtin_amdgcn_sched_barrier(0);
        const int target = 16 * (p + 1);
        int prev = __hip_atomic_fetch_add(&bar->cnt, 1, __ATOMIC_RELAXED, __HIP_MEMORY_SCOPE_AGENT);
        if (prev != target - 1) {
          while (__hip_atomic_load(&bar->cnt, __ATOMIC_RELAXED, __HIP_MEMORY_SCOPE_AGENT) < target) { }
        }
        __builtin_amdgcn_sched_barrier(0);
      }
      __syncthreads();
    }
  }
}

__global__ __launch_bounds__(256, 1) void k_lstm(
    const float* sW0, const float* sb0, const float* sW1, const float* sb1,
    const float* bW0, const float* bb0, const float* bW1, const float* bb1,
    const float* aW0, const float* ab0, const float* aW1, const float* ab1,
    const bf16* stack_emb, const bf16* buff_emb, const float* hist_tab, const int* hist_id,
    const int* len_s, const int* len_b, const int* len_a,
    bf16* h0buf, bf16* h1buf, BarT* bars, BarT* cbars, int* taken, int* xcctab, int* probes)
{
  __shared__ __align__(16) char sm[143872];
  __shared__ int s_role[3];
  const int tid = threadIdx.x;

  if (tid == 0) {
    // HW_REG_XCC_ID: id=20, offset=0, size=4 -> imm = 20 | (3<<11) = 6164
    int xcc = __builtin_amdgcn_s_getreg(6164) & 0xF;
    int l = -1, r = -1;
    // primary: claim a slot of THIS XCD's LSTM (bounded CAS scan)
    if (xcc < 3) {
      int st = blockIdx.x & 15;
      for (int ii = 0; ii < 16 && l < 0; ++ii) {
        int i = (st + ii) & 15;
        int exp0 = 0;
        if (__hip_atomic_compare_exchange_strong(&taken[xcc * 16 + i], &exp0, 1,
              __ATOMIC_RELAXED, __ATOMIC_RELAXED, __HIP_MEMORY_SCOPE_AGENT)) { l = xcc; r = i; }
      }
    }
    if (l < 0) {
      // timed wait (~100us), then scavenge ANY unclaimed slot (bounded)
      unsigned long long t0 = __builtin_amdgcn_s_memrealtime();  // 100 MHz
      while (__builtin_amdgcn_s_memrealtime() - t0 < 10000ULL) __builtin_amdgcn_s_sleep(16);
      for (int i = 0; i < 48 && l < 0; ++i) {
        int exp0 = 0;
        if (__hip_atomic_compare_exchange_strong(&taken[i], &exp0, 1,
              __ATOMIC_RELAXED, __ATOMIC_RELAXED, __HIP_MEMORY_SCOPE_AGENT)) { l = i >> 4; r = i & 15; }
      }
    }
    s_role[0] = l; s_role[1] = r; s_role[2] = 0;
    if (l >= 0) {
      // publish XCD id (MALL) + probe token (PLAIN store -> stays in my L2)
      __hip_atomic_store(&xcctab[l * 16 + r], xcc + 1, __ATOMIC_RELAXED, __HIP_MEMORY_SCOPE_AGENT);
      int* pp = &probes[l * 16 + r];
      int tok = r + 1;
      asm volatile("global_store_dword %0, %1, off" :: "v"(pp), "v"(tok) : "memory");
      asm volatile("s_waitcnt vmcnt(0)" ::: "memory");
      // one-time claim barrier (MALL path; terminates: all 48 slots claimed)
      __hip_atomic_fetch_add(&cbars[l].cnt, 1, __ATOMIC_RELAXED, __HIP_MEMORY_SCOPE_AGENT);
      while (__hip_atomic_load(&cbars[l].cnt, __ATOMIC_RELAXED, __HIP_MEMORY_SCOPE_AGENT) < 16)
        __builtin_amdgcn_s_sleep(1);
      // COH = (all 16 on my physical XCD) AND (probe visibility via L2 path)
      int myx = xcc + 1, coh = 1;
      for (int i = 0; i < 16; ++i)
        coh &= (__hip_atomic_load(&xcctab[l * 16 + i], __ATOMIC_RELAXED, __HIP_MEMORY_SCOPE_AGENT) == myx);
      for (int i = 0; i < 16; ++i) {
        int* qp = &probes[l * 16 + i];
        int pv;
        asm volatile("global_load_dword %0, %1, off sc0" : "=v"(pv) : "v"(qp) : "memory");
        asm volatile("s_waitcnt vmcnt(0)" ::: "memory");
        coh &= (pv == i + 1);
      }
      s_role[2] = coh;
    }
  }
  __syncthreads();

  const int l = s_role[0];
  if (l < 0) return;
  const int rid = s_role[1], coh = s_role[2];
  const int layer = rid >> 3;
  const int u0    = (rid & 7) * 32;

  BarT* bar = bars + l;
  bf16* h0w = h0buf + l * 2 * 32768;  // [2][128][256]
  bf16* h1w = h1buf + l * 2 * 32768;

  const float *W0_, *b0_, *W1_, *b1_; const bf16* xs_; const int* lenp_;
  if (l == 0)      { W0_ = sW0; b0_ = sb0; W1_ = sW1; b1_ = sb1; xs_ = stack_emb; lenp_ = len_s; }
  else if (l == 1) { W0_ = bW0; b0_ = bb0; W1_ = bW1; b1_ = bb1; xs_ = buff_emb;  lenp_ = len_b; }
  else             { W0_ = aW0; b0_ = ab0; W1_ = aW1; b1_ = ab1; xs_ = nullptr;   lenp_ = len_a; }
  const float* W  = layer ? W1_ : W0_;
  const float* bi = layer ? b1_ : b0_;

  switch (l * 4 + layer * 2 + coh) {
    case  0: lstm_role<0, 0, false>(W, bi, xs_, hist_tab, hist_id, lenp_, h0w, h1w, bar, sm, u0); break;
    case  1: lstm_role<0, 0, true >(W, bi, xs_, hist_tab, hist_id, lenp_, h0w, h1w, bar, sm, u0); break;
    case  2: lstm_role<0, 1, false>(W, bi, xs_, hist_tab, hist_id, lenp_, h0w, h1w, bar, sm, u0); break;
    case  3: lstm_role<0, 1, true >(W, bi, xs_, hist_tab, hist_id, lenp_, h0w, h1w, bar, sm, u0); break;
    case  4: lstm_role<1, 0, false>(W, bi, xs_, hist_tab, hist_id, lenp_, h0w, h1w, bar, sm, u0); break;
    case  5: lstm_role<1, 0, true >(W, bi, xs_, hist_tab, hist_id, lenp_, h0w, h1w, bar, sm, u0); break;
    case  6: lstm_role<1, 1, false>(W, bi, xs_, hist_tab, hist_id, lenp_, h0w, h1w, bar, sm, u0); break;
    case  7: lstm_role<1, 1, true >(W, bi, xs_, hist_tab, hist_id, lenp_, h0w, h1w, bar, sm, u0); break;
    case  8: lstm_role<2, 0, false>(W, bi, xs_, hist_tab, hist_id, lenp_, h0w, h1w, bar, sm, u0); break;
    case  9: lstm_role<2, 0, true >(W, bi, xs_, hist_tab, hist_id, lenp_, h0w, h1w, bar, sm, u0); break;
    case 10: lstm_role<2, 1, false>(W, bi, xs_, hist_tab, hist_id, lenp_, h0w, h1w, bar, sm, u0); break;
    case 11: lstm_role<2, 1, true >(W, bi, xs_, hist_tab, hist_id, lenp_, h0w, h1w, bar, sm, u0); break;
  }
}

// =====================================================================
// Kernel 4: out = concat(h_s,h_b,h_a) @ fW + fb
// =====================================================================
__global__ __launch_bounds__(128) void k_final(
    const bf16* h1buf, const float* fW, const float* fb, float* out)
{
  __shared__ float hs[768];
  const int b = blockIdx.x, tid = threadIdx.x;
  for (int i = tid; i < 768; i += 128) {
    int L = i >> 8, u = i & 255;
    hs[i] = (float)h1buf[(L * 2 + 1) * 32768 + b * 256 + u];  // final parity = 1 (T even)
  }
  __syncthreads();
  if (tid < NOUT) {
    float acc = fb[tid];
    for (int u = 0; u < 768; ++u) acc += hs[u] * fW[u * NOUT + tid];
    out[b * NOUT + tid] = acc;
  }
}

// =====================================================================
extern "C" void kernel_launch(void* const* d_in, const int* in_sizes, int n_in,
                              void* d_out, int out_size, void* d_ws, size_t ws_size,
                              hipStream_t stream)
{
  (void)in_sizes; (void)n_in; (void)out_size; (void)ws_size;
  char* ws = (char*)d_ws;
  BarT* bars   = (BarT*)ws;                  // 3*128 = 384 (region 512)
  BarT* cbars  = (BarT*)(ws + 512);          // 3*128 = 384 (region 512)
  int*  taken  = (int*)(ws + 1024);          // 48 ints (region 1024..1280)
  int*  xcctab = (int*)(ws + 1280);          // 48 ints (1280..1536)
  int*  probes = (int*)(ws + 1536);          // 48 ints (1536..1792, region to 2048)
  bf16* h0buf  = (bf16*)(ws + 2048);         // 3*2*128*256*2 = 393216
  bf16* h1buf  = (bf16*)(ws + 2048 + 393216);                // 393216 -> ends 788480
  bf16* comp_emb  = (bf16*)(ws + 788480);                    // 98304*128*2 = 25165824
  bf16* buff_emb  = (bf16*)(ws + 788480 + 25165824);         // 8192*128*2  = 2097152
  bf16* stack_emb = (bf16*)(ws + 788480 + 25165824 + 2097152); // 6144*128*2 = 1572864

  hipMemsetAsync(ws, 0, 788480, stream);  // control block + h0/h1 init state

  k_emb<<<1664, 256, 0, stream>>>(
      (const int*)d_in[0], (const int*)d_in[1], (const int*)d_in[2], (const int*)d_in[3],
      (const float*)d_in[13], (const float*)d_in[10], (const float*)d_in[14], (const float*)d_in[15],
      comp_emb, buff_emb);

  k_compose<<<384, 256, 0, stream>>>(
      (const int*)d_in[2], (const int*)d_in[4], (const int*)d_in[5],
      comp_emb, (const float*)d_in[11], (const float*)d_in[16], (const float*)d_in[17],
      stack_emb);

  k_lstm<<<256, 256, 0, stream>>>(
      (const float*)d_in[18], (const float*)d_in[19], (const float*)d_in[20], (const float*)d_in[21],
      (const float*)d_in[22], (const float*)d_in[23], (const float*)d_in[24], (const float*)d_in[25],
      (const float*)d_in[26], (const float*)d_in[27], (const float*)d_in[28], (const float*)d_in[29],
      stack_emb, buff_emb, (const float*)d_in[12], (const int*)d_in[6],
      (const int*)d_in[7], (const int*)d_in[8], (const int*)d_in[9],
      h0buf, h1buf, bars, cbars, taken, xcctab, probes);

  k_final<<<128, 128, 0, stream>>>(h1buf, (const float*)d_in[30], (const float*)d_in[31],
                                   (float*)d_out);
}